// Round 10
// baseline (185.179 us; speedup 1.0000x reference)
//
#include <hip/hip_runtime.h>
#include <hip/hip_bf16.h>
#include <stdint.h>

// DeformableBlock: fused [offset-conv (MFMA) + meta + deformable conv (MFMA GEMM)
// + GN partial stats] -> GN apply + ReLU.  B=4, CIN=COUT=256, H=W=64, 3x3, GN=32.
// Round 10: 512-thread blocks (16 waves/CU, grid-size was the occupancy limiter),
// GN stats fused into conv epilogue via per-wave reduce + atomics, prep merged.

typedef unsigned short u16;
typedef __bf16 bf16x8 __attribute__((ext_vector_type(8)));
typedef float f32x4_t __attribute__((ext_vector_type(4)));

#define HW 4096

__device__ __forceinline__ uint32_t f32_to_bf16_rne(float f) {
  uint32_t u = __builtin_bit_cast(uint32_t, f);
  return (u + 0x7FFFu + ((u >> 16) & 1u)) >> 16;
}
__device__ __forceinline__ float bf_lo(uint32_t u) {
  return __builtin_bit_cast(float, u << 16);
}
__device__ __forceinline__ float bf_hi(uint32_t u) {
  return __builtin_bit_cast(float, u & 0xFFFF0000u);
}

// ---------------- Kernel T: x NCHW f32 -> NHWC bf16 ----------------
__global__ __launch_bounds__(256) void k_transpose(const float* __restrict__ x,
                                                   u16* __restrict__ xt) {
  __shared__ float tile[32][33];
  int b = blockIdx.z;
  int c0 = blockIdx.y * 32;
  int p0 = blockIdx.x * 32;
  int tx = threadIdx.x, ty = threadIdx.y;  // 32 x 8
#pragma unroll
  for (int j = 0; j < 32; j += 8)
    tile[ty + j][tx] = x[(b * 256 + c0 + ty + j) * HW + p0 + tx];
  __syncthreads();
  int wid = ty * 32 + tx;
  int cp = wid & 15;
  int pr = wid >> 4;
#pragma unroll
  for (int j = 0; j < 2; j++) {
    int p = pr + j * 16;
    uint32_t lo = f32_to_bf16_rne(tile[cp * 2][p]);
    uint32_t hi = f32_to_bf16_rne(tile[cp * 2 + 1][p]);
    *(uint32_t*)&xt[(b * HW + p0 + p) * 256 + c0 + cp * 2] = lo | (hi << 16);
  }
}

// ---------------- Kernel P: merged weight prep + stats zero ----------------
// blocks [0,2304): warr[kc36][g8][m256][kk8]; [2304,2592): owm[kc36][g8][m32][kk8]
// (m<18 real, else 0); block 2592: zero part[256].
__global__ __launch_bounds__(256) void k_prep(const float* __restrict__ wsrc,
                                              const float* __restrict__ ow,
                                              u16* __restrict__ warr,
                                              u16* __restrict__ owm,
                                              float* __restrict__ part) {
  int bid = blockIdx.x;
  int tid = threadIdx.x;
  if (bid < 2304) {
    int e = bid * 256 + tid;  // < 589824
    int kk = e & 7, m = (e >> 3) & 255, g = (e >> 11) & 7, kc = e >> 14;
    int cin = (kc & 3) * 64 + g * 8 + kk;
    int tap = kc >> 2;
    warr[e] = (u16)f32_to_bf16_rne(wsrc[m * 2304 + cin * 9 + tap]);
  } else if (bid < 2592) {
    int e = (bid - 2304) * 256 + tid;  // < 73728
    int kk = e & 7, m = (e >> 3) & 31, g = (e >> 8) & 7, kc = e >> 11;
    int cin = (kc & 3) * 64 + g * 8 + kk;
    int tap = kc >> 2;
    float v = (m < 18) ? ow[m * 2304 + cin * 9 + tap] : 0.f;
    owm[e] = (u16)f32_to_bf16_rne(v);
  } else {
    part[tid] = 0.f;
  }
}

// ---------------- Kernel C: FUSED offset-conv + meta + deformable GEMM + GN stats ----------------
// Block = (b, 32-px tile), 512 blocks x 512 threads (8 waves) -> 16 waves/CU.
// Phase A: offset conv M=32,N=32,K=2304; 8 waves split 9 taps, wave-private LDS
// staging (zero barriers). Meta -> LDS. Phase B: GEMM M=256 (32/wave), N=32
// (2x16 subtiles share A frags), B LDS double-buffered, one barrier/chunk.
// Epilogue: store NCHW + per-wave GN partial reduce -> atomicAdd part[].
__global__ __launch_bounds__(512, 4) void k_conv(
    const u16* __restrict__ xt, const u16* __restrict__ warr,
    const u16* __restrict__ owm, const float* __restrict__ ob,
    float* __restrict__ out, float* __restrict__ part) {
  __shared__ char smem[54272];
  u16* stage = (u16*)smem;                   // A: [w8][2112 u16]       (33792 B)
  float* off_part = (float*)(smem + 33792);  // A: [w8][px32][20]       (20480 B)
  int4* ci_s = (int4*)smem;                  // meta/B: [288]           (4608 B)
  float4* mw_s = (float4*)(smem + 4608);     // meta/B: [288]           (4608 B)
  u16* b_s = (u16*)(smem + 9216);            // B: [2buf][2sub][1088]   (8704 B)

  int tid = threadIdx.x;
  int lane = tid & 63;
  int wm = tid >> 6;  // 0..7
  int b = blockIdx.x >> 7;
  int pt = blockIdx.x & 127;
  int p0 = pt * 32;
  int yrow = p0 >> 6, xbase = p0 & 63;

  // ---- Phase A: offset conv; wave w handles taps w (and w+8 for w=0) ----
  {
    u16* st = stage + wm * 2112;
    int q = lane & 15, pq = lane >> 4;
    f32x4_t a2[2][2] = {};
#pragma unroll 1
    for (int tap = wm; tap < 9; tap += 8) {
      int ky = tap / 3, kx = tap % 3;
      int yy = yrow + ky - 1;
      bool vy = (yy >= 0) && (yy < 64);
#pragma unroll
      for (int cc = 0; cc < 4; cc++) {
        int kc = tap * 4 + cc;
#pragma unroll
        for (int i = 0; i < 8; i++) {
          int px = i * 4 + pq;
          int xx2 = xbase + px + kx - 1;
          uint2 v = make_uint2(0u, 0u);
          if (vy && xx2 >= 0 && xx2 < 64)
            v = *(const uint2*)&xt[(b * HW + yy * 64 + xx2) * 256 + cc * 64 + q * 4];
          *(uint2*)&st[(q >> 1) * 264 + px * 8 + (q & 1) * 4] = v;
        }
#pragma unroll
        for (int ks = 0; ks < 2; ks++) {
          int g = ks * 4 + pq;
          const u16* ab = owm + kc * 2048 + g * 256;
#pragma unroll
          for (int s = 0; s < 2; s++) {
            bf16x8 bfr = *(bf16x8*)&st[g * 264 + (s * 16 + q) * 8];
#pragma unroll
            for (int im = 0; im < 2; im++) {
              bf16x8 af = *(const bf16x8*)&ab[(im * 16 + q) * 8];
              a2[s][im] = __builtin_amdgcn_mfma_f32_16x16x32_bf16(af, bfr, a2[s][im], 0, 0, 0);
            }
          }
        }
      }
    }
    // D: col = q (px within sub), row = pq*4+r (+im*16) = oc
#pragma unroll
    for (int s = 0; s < 2; s++)
#pragma unroll
      for (int im = 0; im < 2; im++)
#pragma unroll
        for (int r = 0; r < 4; r++) {
          int oc = im * 16 + pq * 4 + r;
          if (oc < 18) off_part[(wm * 32 + s * 16 + q) * 20 + oc] = a2[s][im][r];
        }
  }
  __syncthreads();
  // ---- meta: 288 = 9 taps x 32 px; into LDS (aliases dead stage) ----
  if (tid < 288) {
    int tap = tid >> 5;
    int px = tid & 31;
    float dy = ob[2 * tap], dx = ob[2 * tap + 1];
#pragma unroll
    for (int wv = 0; wv < 8; wv++) {
      dy += off_part[(wv * 32 + px) * 20 + 2 * tap];
      dx += off_part[(wv * 32 + px) * 20 + 2 * tap + 1];
    }
    int ky = tap / 3, kx = tap % 3;
    int p = p0 + px;
    int yq = p >> 6, xq = p & 63;
    float py = (float)(yq - 1 + ky) + dy;
    float pxx = (float)(xq - 1 + kx) + dx;
    float y0f = floorf(py), x0f = floorf(pxx);
    float ty = py - y0f, tx = pxx - x0f;
    int y0 = (int)y0f, x0 = (int)x0f;
    int y1 = y0 + 1, x1 = x0 + 1;
    float wy0 = 1.f - ty, wy1 = ty, wx0 = 1.f - tx, wx1 = tx;
    bool vy0 = (y0 >= 0) && (y0 < 64), vy1 = (y1 >= 0) && (y1 < 64);
    bool vx0 = (x0 >= 0) && (x0 < 64), vx1 = (x1 >= 0) && (x1 < 64);
    int cy0 = min(max(y0, 0), 63), cy1 = min(max(y1, 0), 63);
    int cx0 = min(max(x0, 0), 63), cx1 = min(max(x1, 0), 63);
    int base = b * HW;
    int4 ci;
    ci.x = (base + cy0 * 64 + cx0) * 256;
    ci.y = (base + cy0 * 64 + cx1) * 256;
    ci.z = (base + cy1 * 64 + cx0) * 256;
    ci.w = (base + cy1 * 64 + cx1) * 256;
    float4 mw;
    mw.x = wy0 * wx0 * ((vy0 && vx0) ? 1.f : 0.f);
    mw.y = wy0 * wx1 * ((vy0 && vx1) ? 1.f : 0.f);
    mw.z = wy1 * wx0 * ((vy1 && vx0) ? 1.f : 0.f);
    mw.w = wy1 * wx1 * ((vy1 && vx1) ? 1.f : 0.f);
    ci_s[tid] = ci;
    mw_s[tid] = mw;
  }
  __syncthreads();

  // ---- Phase B: GEMM M=256 (wave strip 32), N=32 ----
  int q = tid & 15;
  int pxb = tid >> 4;       // 0..31 (one px per thread)
  int sub = pxb >> 4, pxs = pxb & 15;
  f32x4_t acc[2][2] = {};   // [sub][im]
#pragma unroll 1
  for (int tap = 0; tap < 9; tap++) {
    int4 ci = ci_s[tap * 32 + pxb];
    float4 mw4 = mw_s[tap * 32 + pxb];
#pragma unroll
    for (int cc = 0; cc < 4; cc++) {
      int kc = tap * 4 + cc;
      int e = cc * 64 + q * 4;
      u16* bb = b_s + (kc & 1) * 2176;
      {
        uint2 c0v = *(const uint2*)&xt[ci.x + e];
        uint2 c1v = *(const uint2*)&xt[ci.y + e];
        uint2 c2v = *(const uint2*)&xt[ci.z + e];
        uint2 c3v = *(const uint2*)&xt[ci.w + e];
        float r0 = mw4.x * bf_lo(c0v.x) + mw4.y * bf_lo(c1v.x) + mw4.z * bf_lo(c2v.x) + mw4.w * bf_lo(c3v.x);
        float r1 = mw4.x * bf_hi(c0v.x) + mw4.y * bf_hi(c1v.x) + mw4.z * bf_hi(c2v.x) + mw4.w * bf_hi(c3v.x);
        float r2 = mw4.x * bf_lo(c0v.y) + mw4.y * bf_lo(c1v.y) + mw4.z * bf_lo(c2v.y) + mw4.w * bf_lo(c3v.y);
        float r3 = mw4.x * bf_hi(c0v.y) + mw4.y * bf_hi(c1v.y) + mw4.z * bf_hi(c2v.y) + mw4.w * bf_hi(c3v.y);
        uint2 u;
        u.x = f32_to_bf16_rne(r0) | (f32_to_bf16_rne(r1) << 16);
        u.y = f32_to_bf16_rne(r2) | (f32_to_bf16_rne(r3) << 16);
        *(uint2*)&bb[sub * 1088 + (q >> 1) * 136 + pxs * 8 + (q & 1) * 4] = u;
      }
      __syncthreads();
#pragma unroll
      for (int ks = 0; ks < 2; ks++) {
        int g = ks * 4 + (lane >> 4);
        bf16x8 b0 = *(bf16x8*)&bb[g * 136 + (lane & 15) * 8];
        bf16x8 b1 = *(bf16x8*)&bb[1088 + g * 136 + (lane & 15) * 8];
        const u16* ab = warr + kc * 16384 + g * 2048 + (wm * 32 + (lane & 15)) * 8;
#pragma unroll
        for (int im = 0; im < 2; im++) {
          bf16x8 af = *(const bf16x8*)&ab[im * 128];
          acc[0][im] = __builtin_amdgcn_mfma_f32_16x16x32_bf16(af, b0, acc[0][im], 0, 0, 0);
          acc[1][im] = __builtin_amdgcn_mfma_f32_16x16x32_bf16(af, b1, acc[1][im], 0, 0, 0);
        }
      }
      // no trailing barrier: next cc writes the other buffer (2-deep rotation safe)
    }
  }
  // ---- epilogue: store NCHW + GN partial stats ----
  int rq = lane >> 4;
#pragma unroll
  for (int s = 0; s < 2; s++) {
    int n = p0 + s * 16 + (lane & 15);
#pragma unroll
    for (int im = 0; im < 2; im++)
#pragma unroll
      for (int r = 0; r < 4; r++) {
        int m = wm * 32 + im * 16 + rq * 4 + r;
        out[(b * 256 + m) * HW + n] = acc[s][im][r];
      }
  }
#pragma unroll
  for (int im = 0; im < 2; im++) {
    float s = 0.f, ss = 0.f;
#pragma unroll
    for (int sb = 0; sb < 2; sb++)
#pragma unroll
      for (int r = 0; r < 4; r++) {
        float v = acc[sb][im][r];
        s += v;
        ss += v * v;
      }
    // lanes 0-31 (rq 0,1) -> group wm*4+im*2; lanes 32-63 (rq 2,3) -> +1
#pragma unroll
    for (int mk = 1; mk < 32; mk <<= 1) {
      s += __shfl_xor(s, mk);
      ss += __shfl_xor(ss, mk);
    }
    if ((lane & 31) == 0) {
      int grp = wm * 4 + im * 2 + (lane >> 5);
      atomicAdd(&part[b * 32 + grp], s);
      atomicAdd(&part[128 + b * 32 + grp], ss);
    }
  }
}

// ---------------- Kernel N: finalize stats + normalize + ReLU in place ----------------
__global__ __launch_bounds__(256) void k_gn_apply(float* __restrict__ out,
                                                  const float* __restrict__ part,
                                                  const float* __restrict__ gamma,
                                                  const float* __restrict__ beta) {
  __shared__ float sga, sbe;
  int gid = blockIdx.x * 256 + threadIdx.x;  // float4 index, < 1048576
  int c = (gid >> 10) & 255;
  int bb = gid >> 18;
  if (threadIdx.x == 0) {
    int bg = bb * 32 + (c >> 3);
    float s = part[bg];
    float ss = part[128 + bg];
    float mu = s / 32768.f;
    float var = ss / 32768.f - mu * mu;
    float rs = rsqrtf(var + 1e-5f);
    float ga = gamma[c] * rs;
    sga = ga;
    sbe = beta[c] - mu * ga;
  }
  __syncthreads();
  float ga = sga, be = sbe;
  float4 v = ((const float4*)out)[gid];
  v.x = fmaxf(v.x * ga + be, 0.f);
  v.y = fmaxf(v.y * ga + be, 0.f);
  v.z = fmaxf(v.z * ga + be, 0.f);
  v.w = fmaxf(v.w * ga + be, 0.f);
  ((float4*)out)[gid] = v;
}

extern "C" void kernel_launch(void* const* d_in, const int* in_sizes, int n_in,
                              void* d_out, int out_size, void* d_ws, size_t ws_size,
                              hipStream_t stream) {
  const float* x = (const float*)d_in[0];
  const float* offset_w = (const float*)d_in[1];
  const float* offset_b = (const float*)d_in[2];
  const float* deform_w = (const float*)d_in[3];
  const float* gn_gamma = (const float*)d_in[4];
  const float* gn_beta = (const float*)d_in[5];
  float* out = (float*)d_out;
  char* ws = (char*)d_ws;

  u16* xt = (u16*)ws;                      //  8,388,608 B (bf16 NHWC)
  u16* warr = (u16*)(ws + 8388608);        //  1,179,648 B
  u16* owm = (u16*)(ws + 9568256);         //    147,456 B
  float* part = (float*)(ws + 9715712);    //      1,024 B (s[128], ss[128])

  k_transpose<<<dim3(128, 8, 4), dim3(32, 8), 0, stream>>>(x, xt);
  k_prep<<<dim3(2593), dim3(256), 0, stream>>>(deform_w, offset_w, warr, owm, part);
  k_conv<<<dim3(512), dim3(512), 0, stream>>>(xt, warr, owm, offset_b, out, part);
  k_gn_apply<<<dim3(4096), dim3(256), 0, stream>>>(out, part, gn_gamma, gn_beta);
}